// Round 3
// baseline (660.903 us; speedup 1.0000x reference)
//
#include <hip/hip_runtime.h>

// Problem constants (fixed by setup_inputs)
#define Bb 32
#define Cc 4
#define Hh 512
#define Ww 512
#define Tt 64
#define HW (Hh * Ww)                         // 262144 = 2^18
#define NTOT ((long long)Bb * Cc * Hh * Ww)  // 33,554,432 = 2^25
#define NVEC (NTOT / 4)                      // 8,388,608 float4 pairs
#define BLOCK 256
#define UNROLL 8                             // float4-pairs per thread
#define GRID (NVEC / (BLOCK * UNROLL))       // 4096 blocks, exact cover

// ws layout:
//   [0 .. GRID*8)       : double partials[GRID]   (32 KB)
//   [32768]             : uint32 counter
//   [65536 .. +1 MiB)   : uint64 rowmask[B*H][8]
#define COUNTER_OFF 32768
#define ROWMASK_OFF 65536

// ---------------------------------------------------------------------------
// Kernel 1: per-(b,h) column bitmask. One block per image b; tokens staged in
// LDS; each thread builds 2 adjacent rows (coalesced 16-B stores). Block 0
// thread 0 zeroes the completion counter (ws is re-poisoned every launch).
// ---------------------------------------------------------------------------
__global__ __launch_bounds__(256) void build_rowmask_kernel(
    const float* __restrict__ pos,              // [B, T, 2] (x, y)
    unsigned long long* __restrict__ rowmask,   // [B*H][8]
    unsigned int* __restrict__ counter)
{
    int b   = blockIdx.x;
    int tid = threadIdx.x;

    if (b == 0 && tid == 0) *counter = 0u;

    __shared__ int s_ylo[Tt], s_yhi[Tt], s_xlo[Tt], s_xhi[Tt];
    if (tid < Tt) {
        const float2 xy = ((const float2*)pos)[b * Tt + tid];
        bool valid = (xy.x > 0.0f) && (xy.y > 0.0f);
        int xp = (int)floorf(xy.x * (float)Ww);
        int yp = (int)floorf(xy.y * (float)Hh);
        int xlo = xp - 5; if (xlo < 0) xlo = 0;
        int xhi = xp + 5; if (xhi > Ww) xhi = Ww;
        if (!valid) { xlo = 0; xhi = 0; }
        s_ylo[tid] = valid ? yp - 5 : (1 << 30);
        s_yhi[tid] = valid ? yp + 5 : -(1 << 30);
        s_xlo[tid] = xlo;
        s_xhi[tid] = xhi;
    }
    __syncthreads();

#pragma unroll
    for (int r = 0; r < 2; ++r) {
        int h = 2 * tid + r;                    // 0..511
        unsigned long long m[8];
#pragma unroll
        for (int i = 0; i < 8; ++i) m[i] = 0ull;

        for (int t = 0; t < Tt; ++t) {
            if (h < s_ylo[t] || h >= s_yhi[t]) continue;
            int xlo = s_xlo[t], xhi = s_xhi[t];
            if (xlo >= xhi) continue;
            int w0 = xlo >> 6;
            int w1 = (xhi - 1) >> 6;
            for (int wd = w0; wd <= w1; ++wd) {
                int lo = xlo - (wd << 6); if (lo < 0) lo = 0;
                int hi = xhi - (wd << 6); if (hi > 64) hi = 64;
                m[wd] |= (((1ull << (hi - lo)) - 1ull) << lo);  // hi-lo <= 10
            }
        }

        ulonglong2* out = (ulonglong2*)(rowmask + ((size_t)b * Hh + h) * 8);
#pragma unroll
        for (int i = 0; i < 4; ++i)
            out[i] = make_ulonglong2(m[2 * i], m[2 * i + 1]);
    }
}

// ---------------------------------------------------------------------------
// Kernel 2: flat-indexed weighted squared-difference reduction + last-block
// finalize. Thread loads 8 float4 from each tensor + 8 mask words into
// explicit arrays (24 independent loads, all issued before any use) to
// maximize memory-level parallelism. Block covers 2048 consecutive float4s.
// ---------------------------------------------------------------------------
__global__ __launch_bounds__(256) void weighted_sq_sum_kernel(
    const float4* __restrict__ pred4,
    const float4* __restrict__ targ4,
    const unsigned long long* __restrict__ rowmask,
    double* __restrict__ partials,
    unsigned int* __restrict__ counter,
    float* __restrict__ out)
{
    const int tid = threadIdx.x;
    const int g0  = blockIdx.x * (BLOCK * UNROLL) + tid;  // first float4 index

    float4 A[UNROLL], Bv[UNROLL];
    unsigned long long Wd[UNROLL];
    int sh[UNROLL];

    // ---- issue all independent loads first ----
#pragma unroll
    for (int i = 0; i < UNROLL; ++i)
        A[i] = pred4[g0 + i * BLOCK];
#pragma unroll
    for (int i = 0; i < UNROLL; ++i)
        Bv[i] = targ4[g0 + i * BLOCK];
#pragma unroll
    for (int i = 0; i < UNROLL; ++i) {
        unsigned int e = (unsigned int)(g0 + i * BLOCK) << 2;  // element index
        // word = ((b*512 + h)*8 + (w>>6));  b=e>>20, h=(e>>9)&511, w=e&511
        unsigned int widx = ((e >> 20) << 12) | (((e >> 9) & 511u) << 3) |
                            ((e >> 6) & 7u);
        Wd[i] = rowmask[widx];
        sh[i] = (int)(e & 63u);
    }

    // ---- compute ----
    float sfull = 0.f, smask = 0.f;
#pragma unroll
    for (int i = 0; i < UNROLL; ++i) {
        float dx = A[i].x - Bv[i].x;
        float dy = A[i].y - Bv[i].y;
        float dz = A[i].z - Bv[i].z;
        float dw = A[i].w - Bv[i].w;
        float sx = dx * dx, sy = dy * dy, sz = dz * dz, sw = dw * dw;
        sfull += sx + sy + sz + sw;
        unsigned long long word = Wd[i] >> sh[i];
        smask += (word & 1ull) ? sx : 0.f;
        smask += ((word >> 1) & 1ull) ? sy : 0.f;
        smask += ((word >> 2) & 1ull) ? sz : 0.f;
        smask += ((word >> 3) & 1ull) ? sw : 0.f;
    }

    double v = (double)sfull + 3.0 * (double)smask;

    // wave (64-lane) reduction
#pragma unroll
    for (int off = 32; off > 0; off >>= 1)
        v += __shfl_down(v, off, 64);

    __shared__ double lsum[4];
    __shared__ int lastFlag;
    int lane = tid & 63;
    int wid  = tid >> 6;
    if (lane == 0) lsum[wid] = v;
    __syncthreads();

    if (tid == 0) {
        double p = lsum[0] + lsum[1] + lsum[2] + lsum[3];
        __hip_atomic_store(&partials[blockIdx.x], p, __ATOMIC_RELEASE,
                           __HIP_MEMORY_SCOPE_AGENT);
        unsigned int old = __hip_atomic_fetch_add(counter, 1u, __ATOMIC_ACQ_REL,
                                                  __HIP_MEMORY_SCOPE_AGENT);
        lastFlag = (old == (unsigned int)(gridDim.x - 1));
    }
    __syncthreads();

    if (lastFlag) {
        double s = 0.0;
#pragma unroll
        for (int i = 0; i < GRID / BLOCK; ++i)   // 16 iterations
            s += __hip_atomic_load(&partials[i * BLOCK + tid], __ATOMIC_RELAXED,
                                   __HIP_MEMORY_SCOPE_AGENT);
#pragma unroll
        for (int off = 32; off > 0; off >>= 1)
            s += __shfl_down(s, off, 64);
        __syncthreads();                          // reuse lsum safely
        if (lane == 0) lsum[wid] = s;
        __syncthreads();
        if (tid == 0)
            out[0] = (float)((lsum[0] + lsum[1] + lsum[2] + lsum[3]) *
                             (1.0 / (double)NTOT));
    }
}

extern "C" void kernel_launch(void* const* d_in, const int* in_sizes, int n_in,
                              void* d_out, int out_size, void* d_ws, size_t ws_size,
                              hipStream_t stream) {
    const float4* pred = (const float4*)d_in[0];   // [32,4,512,512] f32
    const float4* targ = (const float4*)d_in[1];   // [32,4,512,512] f32
    // d_in[2] = text_tokens (unused by the loss)
    const float* pos   = (const float*)d_in[3];    // [32,64,2] f32

    double* partials = (double*)d_ws;
    unsigned int* counter = (unsigned int*)((char*)d_ws + COUNTER_OFF);
    unsigned long long* rowmask =
        (unsigned long long*)((char*)d_ws + ROWMASK_OFF);
    float* out = (float*)d_out;

    build_rowmask_kernel<<<Bb, BLOCK, 0, stream>>>(pos, rowmask, counter);
    weighted_sq_sum_kernel<<<GRID, BLOCK, 0, stream>>>(pred, targ, rowmask,
                                                       partials, counter, out);
}

// Round 4
// 299.143 us; speedup vs baseline: 2.2093x; 2.2093x over previous
//
#include <hip/hip_runtime.h>

// Problem constants (fixed by setup_inputs)
#define Bb 32
#define Cc 4
#define Hh 512
#define Ww 512
#define Tt 64
#define HW (Hh * Ww)                         // 262144 = 2^18
#define NTOT ((long long)Bb * Cc * Hh * Ww)  // 33,554,432 = 2^25
#define NVEC (NTOT / 4)                      // 8,388,608 float4 pairs
#define BLOCK 256
#define UNROLL 16                            // float4-pairs per thread
#define GRID (NVEC / (BLOCK * UNROLL))       // 2048 blocks, exact cover

// ws layout:
//   [0 .. GRID*8)       : double partials[GRID]   (16 KB)
//   [65536 .. +1 MiB)   : uint64 rowmask[B*H][8]
#define ROWMASK_OFF 65536

// ---------------------------------------------------------------------------
// Kernel 1: per-(b,h) column bitmask. One block per image b; tokens staged in
// LDS; each thread builds 2 adjacent rows (coalesced 16-B stores).
// ---------------------------------------------------------------------------
__global__ __launch_bounds__(256) void build_rowmask_kernel(
    const float* __restrict__ pos,              // [B, T, 2] (x, y)
    unsigned long long* __restrict__ rowmask)   // [B*H][8]
{
    int b   = blockIdx.x;
    int tid = threadIdx.x;

    __shared__ int s_ylo[Tt], s_yhi[Tt], s_xlo[Tt], s_xhi[Tt];
    if (tid < Tt) {
        const float2 xy = ((const float2*)pos)[b * Tt + tid];
        bool valid = (xy.x > 0.0f) && (xy.y > 0.0f);
        int xp = (int)floorf(xy.x * (float)Ww);
        int yp = (int)floorf(xy.y * (float)Hh);
        int xlo = xp - 5; if (xlo < 0) xlo = 0;
        int xhi = xp + 5; if (xhi > Ww) xhi = Ww;
        if (!valid) { xlo = 0; xhi = 0; }
        s_ylo[tid] = valid ? yp - 5 : (1 << 30);
        s_yhi[tid] = valid ? yp + 5 : -(1 << 30);
        s_xlo[tid] = xlo;
        s_xhi[tid] = xhi;
    }
    __syncthreads();

#pragma unroll
    for (int r = 0; r < 2; ++r) {
        int h = 2 * tid + r;                    // 0..511
        unsigned long long m[8];
#pragma unroll
        for (int i = 0; i < 8; ++i) m[i] = 0ull;

        for (int t = 0; t < Tt; ++t) {
            if (h < s_ylo[t] || h >= s_yhi[t]) continue;
            int xlo = s_xlo[t], xhi = s_xhi[t];
            if (xlo >= xhi) continue;
            int w0 = xlo >> 6;
            int w1 = (xhi - 1) >> 6;
            for (int wd = w0; wd <= w1; ++wd) {
                int lo = xlo - (wd << 6); if (lo < 0) lo = 0;
                int hi = xhi - (wd << 6); if (hi > 64) hi = 64;
                m[wd] |= (((1ull << (hi - lo)) - 1ull) << lo);  // hi-lo <= 10
            }
        }

        ulonglong2* out = (ulonglong2*)(rowmask + ((size_t)b * Hh + h) * 8);
#pragma unroll
        for (int i = 0; i < 4; ++i)
            out[i] = make_ulonglong2(m[2 * i], m[2 * i + 1]);
    }
}

// ---------------------------------------------------------------------------
// Kernel 2: flat-indexed weighted squared-difference partial reduction.
// Thread loads 16 float4 from each tensor + 16 mask words, all issued before
// any use (33 loads ~ 8.5 KB in flight per wave -> latency covered).
// NO device-scope atomics (R2/R3 showed ~130 ns/block of serialized cache-
// maintenance from agent-scope release/acq_rel ops — that was the regression).
// ---------------------------------------------------------------------------
__global__ __launch_bounds__(256) void weighted_sq_sum_kernel(
    const float4* __restrict__ pred4,
    const float4* __restrict__ targ4,
    const unsigned long long* __restrict__ rowmask,
    double* __restrict__ partials)
{
    const int tid = threadIdx.x;
    const int g0  = blockIdx.x * (BLOCK * UNROLL) + tid;  // first float4 index

    float4 A[UNROLL], Bv[UNROLL];
    unsigned long long Wd[UNROLL];

    // ---- issue all independent loads first ----
#pragma unroll
    for (int i = 0; i < UNROLL; ++i)
        A[i] = pred4[g0 + i * BLOCK];
#pragma unroll
    for (int i = 0; i < UNROLL; ++i)
        Bv[i] = targ4[g0 + i * BLOCK];
#pragma unroll
    for (int i = 0; i < UNROLL; ++i) {
        unsigned int e = (unsigned int)(g0 + i * BLOCK) << 2;  // element index
        // word = ((b*512 + h)*8 + (w>>6));  b=e>>20, h=(e>>9)&511, w=e&511
        unsigned int widx = ((e >> 20) << 12) | (((e >> 9) & 511u) << 3) |
                            ((e >> 6) & 7u);
        Wd[i] = rowmask[widx];
    }

    // ---- compute ----
    float sfull = 0.f, smask = 0.f;
#pragma unroll
    for (int i = 0; i < UNROLL; ++i) {
        float dx = A[i].x - Bv[i].x;
        float dy = A[i].y - Bv[i].y;
        float dz = A[i].z - Bv[i].z;
        float dw = A[i].w - Bv[i].w;
        float sx = dx * dx, sy = dy * dy, sz = dz * dz, sw = dw * dw;
        sfull += sx + sy + sz + sw;
        int shf = (int)(((unsigned int)(g0 + i * BLOCK) << 2) & 63u);
        unsigned long long word = Wd[i] >> shf;
        smask += (word & 1ull) ? sx : 0.f;
        smask += ((word >> 1) & 1ull) ? sy : 0.f;
        smask += ((word >> 2) & 1ull) ? sz : 0.f;
        smask += ((word >> 3) & 1ull) ? sw : 0.f;
    }

    double v = (double)sfull + 3.0 * (double)smask;

    // wave (64-lane) reduction
#pragma unroll
    for (int off = 32; off > 0; off >>= 1)
        v += __shfl_down(v, off, 64);

    __shared__ double lsum[4];
    int lane = tid & 63;
    int wid  = tid >> 6;
    if (lane == 0) lsum[wid] = v;
    __syncthreads();
    if (tid == 0)
        partials[blockIdx.x] = lsum[0] + lsum[1] + lsum[2] + lsum[3];
}

// ---------------------------------------------------------------------------
// Kernel 3: reduce GRID partials, scale by 1/N, write scalar fp32 output.
// ---------------------------------------------------------------------------
__global__ __launch_bounds__(256) void final_reduce_kernel(
    const double* __restrict__ partials, float* __restrict__ out)
{
    double t[GRID / BLOCK];                    // 8 independent loads
#pragma unroll
    for (int i = 0; i < GRID / BLOCK; ++i)
        t[i] = partials[i * BLOCK + threadIdx.x];
    double v = 0.0;
#pragma unroll
    for (int i = 0; i < GRID / BLOCK; ++i) v += t[i];

#pragma unroll
    for (int off = 32; off > 0; off >>= 1)
        v += __shfl_down(v, off, 64);
    __shared__ double lsum[4];
    int lane = threadIdx.x & 63;
    int wid  = threadIdx.x >> 6;
    if (lane == 0) lsum[wid] = v;
    __syncthreads();
    if (threadIdx.x == 0)
        out[0] = (float)((lsum[0] + lsum[1] + lsum[2] + lsum[3]) *
                         (1.0 / (double)NTOT));
}

extern "C" void kernel_launch(void* const* d_in, const int* in_sizes, int n_in,
                              void* d_out, int out_size, void* d_ws, size_t ws_size,
                              hipStream_t stream) {
    const float4* pred = (const float4*)d_in[0];   // [32,4,512,512] f32
    const float4* targ = (const float4*)d_in[1];   // [32,4,512,512] f32
    // d_in[2] = text_tokens (unused by the loss)
    const float* pos   = (const float*)d_in[3];    // [32,64,2] f32

    double* partials = (double*)d_ws;
    unsigned long long* rowmask =
        (unsigned long long*)((char*)d_ws + ROWMASK_OFF);
    float* out = (float*)d_out;

    build_rowmask_kernel<<<Bb, BLOCK, 0, stream>>>(pos, rowmask);
    weighted_sq_sum_kernel<<<GRID, BLOCK, 0, stream>>>(pred, targ, rowmask,
                                                       partials);
    final_reduce_kernel<<<1, 256, 0, stream>>>(partials, out);
}